// Round 2
// baseline (995.106 us; speedup 1.0000x reference)
//
#include <hip/hip_runtime.h>
#include <stdint.h>

#define D 2048
#define V 4096
#define TINYF 1.17549435e-38f
#define NINF (-__builtin_huge_valf())

// ---------------- threefry (JAX partitionable scheme, verified exact in R1) --------
__device__ __forceinline__ void tf_block(uint32_t k0, uint32_t k1, uint32_t x0, uint32_t x1,
                                         uint32_t& o0, uint32_t& o1) {
  uint32_t ks2 = k0 ^ k1 ^ 0x1BD11BDAu;
  uint32_t ks[3] = {k0, k1, ks2};
  x0 += k0; x1 += k1;
  const uint32_t rotA[4] = {13u, 15u, 26u, 6u};
  const uint32_t rotB[4] = {17u, 29u, 16u, 24u};
#pragma unroll
  for (int i = 0; i < 5; ++i) {
    const uint32_t* rot = (i & 1) ? rotB : rotA;
#pragma unroll
    for (int j = 0; j < 4; ++j) {
      uint32_t r = rot[j];
      x0 += x1;
      x1 = (x1 << r) | (x1 >> (32u - r));
      x1 ^= x0;
    }
    x0 += ks[(i + 1) % 3];
    x1 += ks[(i + 2) % 3] + (uint32_t)(i + 1);
  }
  o0 = x0; o1 = x1;
}

__device__ __forceinline__ float gumbel_at(uint32_t k1, uint32_t k2, int i) {
  uint32_t o0, o1;
  tf_block(k1, k2, 0u, (uint32_t)i, o0, o1);
  uint32_t bits = o0 ^ o1;
  float u = __uint_as_float((bits >> 9) | 0x3F800000u) - 1.0f;
  u = fmaxf(TINYF, u + TINYF);
  return -logf(-logf(u));
}

// ---------------- row-dot helpers (f32 and bf16 weight rows vs LDS f32 vector) -----
__device__ __forceinline__ float row_dot(const float* __restrict__ row,
                                         const float* __restrict__ xs, int lane) {
  float a = 0.f;
#pragma unroll
  for (int k = lane * 4; k < D; k += 256) {
    float4 w = *(const float4*)(row + k);
    float4 x = *(const float4*)(xs + k);
    a += w.x * x.x + w.y * x.y + w.z * x.z + w.w * x.w;
  }
  return a;
}

__device__ __forceinline__ float row_dot(const uint16_t* __restrict__ row,
                                         const float* __restrict__ xs, int lane) {
  float a = 0.f;
#pragma unroll
  for (int k = lane * 8; k < D; k += 512) {
    uint4 u = *(const uint4*)(row + k);
    float4 x0 = *(const float4*)(xs + k);
    float4 x1 = *(const float4*)(xs + k + 4);
    a += __uint_as_float(u.x << 16) * x0.x + __uint_as_float(u.x & 0xFFFF0000u) * x0.y;
    a += __uint_as_float(u.y << 16) * x0.z + __uint_as_float(u.y & 0xFFFF0000u) * x0.w;
    a += __uint_as_float(u.z << 16) * x1.x + __uint_as_float(u.z & 0xFFFF0000u) * x1.y;
    a += __uint_as_float(u.w << 16) * x1.z + __uint_as_float(u.w & 0xFFFF0000u) * x1.w;
  }
  return a;
}

// ---------------- init: zero the tail-block counters ------------------------------
__global__ void init_k(int* __restrict__ c) {
  if (threadIdx.x < 16) c[threadIdx.x] = 0;
}

// ---------------- f32 -> bf16 (RNE) weight pack: w_ih, w_hh, lin1_w, lin2_w --------
__global__ void convert_k(const float* __restrict__ wih, const float* __restrict__ whh,
                          const float* __restrict__ l1, const float* __restrict__ l2,
                          uint16_t* __restrict__ dwih, uint16_t* __restrict__ dwhh,
                          uint16_t* __restrict__ dl1, uint16_t* __restrict__ dl2) {
  size_t gid = (size_t)blockIdx.x * 256 + threadIdx.x;  // 8-float chunk id
  const size_t C1 = (size_t)4 * D * D / 8;              // w_ih chunks
  const size_t C2 = 2 * C1;
  const size_t C3 = C2 + (size_t)D * D / 8;
  const size_t C4 = C3 + (size_t)D * D / 8;
  const float* src; uint16_t* dst; size_t off;
  if (gid < C1)      { src = wih; dst = dwih; off = gid; }
  else if (gid < C2) { src = whh; dst = dwhh; off = gid - C1; }
  else if (gid < C3) { src = l1;  dst = dl1;  off = gid - C2; }
  else if (gid < C4) { src = l2;  dst = dl2;  off = gid - C3; }
  else return;
  const float4* s = (const float4*)(src + off * 8);
  float4 a = s[0], b = s[1];
  float v[8] = {a.x, a.y, a.z, a.w, b.x, b.y, b.z, b.w};
  uint32_t r[8];
#pragma unroll
  for (int t = 0; t < 8; ++t) {
    uint32_t x = __float_as_uint(v[t]);
    x = x + 0x7FFFu + ((x >> 16) & 1u);   // round-to-nearest-even
    r[t] = x >> 16;
  }
  uint4 o;
  o.x = r[0] | (r[1] << 16);
  o.y = r[2] | (r[3] << 16);
  o.z = r[4] | (r[5] << 16);
  o.w = r[6] | (r[7] << 16);
  *(uint4*)(dst + off * 8) = o;
}

// ---------------- LSTM cell: wave per output row, 4 rows/block ---------------------
template <typename WT>
__global__ void lstm_cell_k(const WT* __restrict__ w_ih, const WT* __restrict__ w_hh,
                            const float* __restrict__ b_ih, const float* __restrict__ b_hh,
                            const float* __restrict__ x_base, const int* __restrict__ x_idx,
                            const float* __restrict__ h_in, const float* __restrict__ c_in,
                            float* __restrict__ h_out, float* __restrict__ c_out,
                            float* __restrict__ c_copy) {
  __shared__ float xs[D];
  __shared__ float hs[D];
  int tid = threadIdx.x;
  const float* x = x_base;
  if (x_idx) x += (size_t)(*x_idx) * D;
  for (int i = tid; i < D; i += 256) { xs[i] = x[i]; hs[i] = h_in ? h_in[i] : 0.f; }
  __syncthreads();
  int wave = tid >> 6, lane = tid & 63;
  int j = blockIdx.x * 4 + wave;
  float gv[4];
#pragma unroll
  for (int m = 0; m < 4; ++m) {
    float a = row_dot(w_ih + (size_t)(m * D + j) * D, xs, lane)
            + row_dot(w_hh + (size_t)(m * D + j) * D, hs, lane);
#pragma unroll
    for (int off = 32; off > 0; off >>= 1) a += __shfl_down(a, off, 64);
    gv[m] = a + b_ih[m * D + j] + b_hh[m * D + j];
  }
  if (lane == 0) {
    float ig = 1.f / (1.f + expf(-gv[0]));
    float fg = 1.f / (1.f + expf(-gv[1]));
    float gg = tanhf(gv[2]);
    float og = 1.f / (1.f + expf(-gv[3]));
    float ci = c_in ? c_in[j] : 0.f;
    float cn = fg * ci + ig * gg;
    float hn = og * tanhf(cn);
    c_out[j] = cn;
    h_out[j] = hn;
    if (c_copy) c_copy[j] = cn;
  }
}

// ---------------- lin1 + lin2 GEMVs, tail block does attn logits + sample ----------
template <typename WT>
__global__ void lin12_k(const WT* __restrict__ l1w, const float* __restrict__ l1b,
                        const WT* __restrict__ l2w, const float* __restrict__ l2b,
                        const float* __restrict__ c, float* __restrict__ all_cw,
                        float* __restrict__ qb, int layer,
                        const float* __restrict__ lin3_w, const float* __restrict__ lin3_b,
                        int* __restrict__ counter, int step,
                        float* __restrict__ out_arc, float* __restrict__ out_ent,
                        float* __restrict__ out_lp, int* __restrict__ sel_out) {
  __shared__ float xs[D];
  __shared__ float red[256];
  __shared__ float sl[8];
  __shared__ int islast;
  int tid = threadIdx.x;
  for (int i = tid; i < D; i += 256) xs[i] = c[i];
  __syncthreads();
  int wave = tid >> 6, lane = tid & 63;
  int b = blockIdx.x;
  const WT* Wp; const float* bp; float* dst; int row;
  if (b < 512) { row = b * 4 + wave; Wp = l1w; bp = l1b; dst = all_cw + (size_t)layer * D; }
  else         { row = (b - 512) * 4 + wave; Wp = l2w; bp = l2b; dst = qb; }
  float a = row_dot(Wp + (size_t)row * D, xs, lane);
#pragma unroll
  for (int off = 32; off > 0; off >>= 1) a += __shfl_down(a, off, 64);
  if (lane == 0) dst[row] = a + bp[row];
  __threadfence();
  if (tid == 0) islast = (atomicAdd(counter, 1) == (int)gridDim.x - 1);
  __syncthreads();
  if (!islast) return;
  __threadfence();
  // attention logits over t = 0..layer
  int N = layer + 1;
  for (int t = 0; t < N; ++t) {
    float s = 0.f;
    for (int k = tid; k < D; k += 256) s += tanhf(qb[k] + all_cw[(size_t)t * D + k]) * lin3_w[k];
    red[tid] = s; __syncthreads();
    for (int st = 128; st > 0; st >>= 1) { if (tid < st) red[tid] += red[tid + st]; __syncthreads(); }
    if (tid == 0) sl[t] = red[0] + lin3_b[0];
    __syncthreads();
  }
  if (tid == 0) {
    uint32_t k1, k2; tf_block(0u, 42u, 0u, (uint32_t)step, k1, k2);
    float m = NINF;
    for (int i = 0; i < N; ++i) m = fmaxf(m, sl[i]);
    float S = 0.f, T = 0.f;
    for (int i = 0; i < N; ++i) { float e = expf(sl[i] - m); S += e; T += e * (sl[i] - m); }
    float L = logf(S);
    float bv = NINF; int bi = 0;
    for (int i = 0; i < N; ++i) {
      float sc = gumbel_at(k1, k2, i) + sl[i];
      if (sc > bv) { bv = sc; bi = i; }
    }
    *out_arc = (float)bi;
    *out_ent = L - T / S;        // = -(sum p*logp)
    *out_lp  = sl[bi] - m - L;
    *sel_out = bi;
  }
}

// ---------------- decoder GEMV (f32), tail block samples over V=4096 ---------------
__global__ void dec_sample_k(const float* __restrict__ W, const float* __restrict__ bias,
                             const float* __restrict__ c, float* __restrict__ logits,
                             int* __restrict__ counter, int step,
                             float* __restrict__ out_arc, float* __restrict__ out_ent,
                             float* __restrict__ out_lp, int* __restrict__ sel_out) {
  __shared__ float xs[D];
  __shared__ float red[256];
  __shared__ int redi[256];
  __shared__ int islast;
  int tid = threadIdx.x;
  for (int i = tid; i < D; i += 256) xs[i] = c[i];
  __syncthreads();
  int wave = tid >> 6, lane = tid & 63;
  int row = blockIdx.x * 4 + wave;
  float a = row_dot(W + (size_t)row * D, xs, lane);
#pragma unroll
  for (int off = 32; off > 0; off >>= 1) a += __shfl_down(a, off, 64);
  if (lane == 0) logits[row] = a + bias[row];
  __threadfence();
  if (tid == 0) islast = (atomicAdd(counter, 1) == (int)gridDim.x - 1);
  __syncthreads();
  if (!islast) return;
  __threadfence();
  uint32_t k1, k2; tf_block(0u, 42u, 0u, (uint32_t)step, k1, k2);
  float xv[16];
  float m = NINF, bv = NINF; int bi = 1 << 30;
#pragma unroll
  for (int t = 0; t < 16; ++t) {
    int i = tid + t * 256;
    float x = logits[i];
    xv[t] = x;
    m = fmaxf(m, x);
    float sc = gumbel_at(k1, k2, i) + x;
    if (sc > bv) { bv = sc; bi = i; }   // within-thread i increasing -> first-index ties
  }
  red[tid] = m; __syncthreads();
  for (int st = 128; st > 0; st >>= 1) { if (tid < st) red[tid] = fmaxf(red[tid], red[tid + st]); __syncthreads(); }
  m = red[0]; __syncthreads();
  float S = 0.f, T = 0.f;
#pragma unroll
  for (int t = 0; t < 16; ++t) { float e = expf(xv[t] - m); S += e; T += e * (xv[t] - m); }
  red[tid] = S; __syncthreads();
  for (int st = 128; st > 0; st >>= 1) { if (tid < st) red[tid] += red[tid + st]; __syncthreads(); }
  S = red[0]; __syncthreads();
  red[tid] = T; __syncthreads();
  for (int st = 128; st > 0; st >>= 1) { if (tid < st) red[tid] += red[tid + st]; __syncthreads(); }
  T = red[0]; __syncthreads();
  red[tid] = bv; redi[tid] = bi; __syncthreads();
  for (int st = 128; st > 0; st >>= 1) {
    if (tid < st) {
      float ov = red[tid + st]; int oi = redi[tid + st];
      if (ov > red[tid] || (ov == red[tid] && oi < redi[tid])) { red[tid] = ov; redi[tid] = oi; }
    }
    __syncthreads();
  }
  if (tid == 0) {
    float L = logf(S);
    int idx = redi[0];
    *out_arc = (float)idx;
    *out_ent = L - T / S;
    *out_lp  = logits[idx] - m - L;
    *sel_out = idx;
  }
}

// ---------------- host-side orchestration ------------------------------------------
extern "C" void kernel_launch(void* const* d_in, const int* in_sizes, int n_in,
                              void* d_out, int out_size, void* d_ws, size_t ws_size,
                              hipStream_t stream) {
  const float* emb0   = (const float*)d_in[0];
  const float* w_ih   = (const float*)d_in[1];
  const float* w_hh   = (const float*)d_in[2];
  const float* b_ih   = (const float*)d_in[3];
  const float* b_hh   = (const float*)d_in[4];
  const float* lin1_w = (const float*)d_in[5];
  const float* lin1_b = (const float*)d_in[6];
  const float* lin2_w = (const float*)d_in[7];
  const float* lin2_b = (const float*)d_in[8];
  const float* lin3_w = (const float*)d_in[9];
  const float* lin3_b = (const float*)d_in[10];
  const float* dec_w  = (const float*)d_in[11];
  const float* dec_b  = (const float*)d_in[12];
  const float* embt   = (const float*)d_in[13];

  float* out = (float*)d_out;  // [0..8]=arc, [9..17]=entropy, [18..26]=log_probs
  float* ws = (float*)d_ws;

  float* hA     = ws;
  float* cA     = ws + D;
  float* hB     = ws + 2 * D;
  float* cB     = ws + 3 * D;
  float* all_c  = ws + 4 * D;      // 4*D
  float* all_cw = ws + 8 * D;      // 4*D
  float* qb     = ws + 12 * D;     // D
  float* logits = ws + 13 * D;     // V = 2*D
  int* counters = (int*)(ws + 15 * D);           // 16 ints
  int* sel_skip = counters + 12;
  int* sel_func = counters + 13;
  uint16_t* wih_bf = (uint16_t*)(ws + 15 * D + 64);
  uint16_t* whh_bf = wih_bf + (size_t)4 * D * D;
  uint16_t* l1_bf  = whh_bf + (size_t)4 * D * D;
  uint16_t* l2_bf  = l1_bf + (size_t)D * D;

  // bf16 weight cache needs ~84 MB of ws; fall back to f32 path if ws is small
  bool bf = ws_size >= ((size_t)95 << 20);

  init_k<<<1, 64, 0, stream>>>(counters);
  if (bf) {
    // total 8-float chunks: (2*4*D*D + 2*D*D) / 8 = 5242880 -> 20480 blocks of 256
    convert_k<<<20480, 256, 0, stream>>>(w_ih, w_hh, lin1_w, lin2_w,
                                         wih_bf, whh_bf, l1_bf, l2_bf);
  }

  float* h_in = nullptr; float* c_in = nullptr;
  float* h_out = hA;     float* c_out = cA;
  int step = 0;

  auto swap_state = [&]() {
    h_in = h_out; c_in = c_out;
    h_out = (h_in == hA) ? hB : hA;
    c_out = (c_in == cA) ? cB : cA;
  };

  for (int layer = 0; layer < 4; ++layer) {
    const float* xb; const int* xi;
    if (layer == 0) { xb = emb0; xi = nullptr; }
    else            { xb = embt + (size_t)(layer - 1) * V * D; xi = sel_func; }
    if (bf) lstm_cell_k<uint16_t><<<D / 4, 256, 0, stream>>>(wih_bf, whh_bf, b_ih, b_hh, xb, xi,
                                                             h_in, c_in, h_out, c_out,
                                                             all_c + (size_t)layer * D);
    else    lstm_cell_k<float><<<D / 4, 256, 0, stream>>>(w_ih, w_hh, b_ih, b_hh, xb, xi,
                                                          h_in, c_in, h_out, c_out,
                                                          all_c + (size_t)layer * D);
    swap_state();

    if (bf) lin12_k<uint16_t><<<1024, 256, 0, stream>>>(l1_bf, lin1_b, l2_bf, lin2_b, c_in,
                                                        all_cw, qb, layer, lin3_w, lin3_b,
                                                        counters + step, step,
                                                        out + step, out + 9 + step, out + 18 + step,
                                                        sel_skip);
    else    lin12_k<float><<<1024, 256, 0, stream>>>(lin1_w, lin1_b, lin2_w, lin2_b, c_in,
                                                     all_cw, qb, layer, lin3_w, lin3_b,
                                                     counters + step, step,
                                                     out + step, out + 9 + step, out + 18 + step,
                                                     sel_skip);
    step++;

    if (bf) lstm_cell_k<uint16_t><<<D / 4, 256, 0, stream>>>(wih_bf, whh_bf, b_ih, b_hh,
                                                             all_c, sel_skip,
                                                             h_in, c_in, h_out, c_out, nullptr);
    else    lstm_cell_k<float><<<D / 4, 256, 0, stream>>>(w_ih, w_hh, b_ih, b_hh,
                                                          all_c, sel_skip,
                                                          h_in, c_in, h_out, c_out, nullptr);
    swap_state();

    dec_sample_k<<<V / 4, 256, 0, stream>>>(dec_w + (size_t)layer * V * D,
                                            dec_b + (size_t)layer * V, c_in, logits,
                                            counters + step, step,
                                            out + step, out + 9 + step, out + 18 + step,
                                            sel_func);
    step++;
  }

  // final cell + decode
  if (bf) lstm_cell_k<uint16_t><<<D / 4, 256, 0, stream>>>(wih_bf, whh_bf, b_ih, b_hh,
                                                           embt + (size_t)3 * V * D, sel_func,
                                                           h_in, c_in, h_out, c_out, nullptr);
  else    lstm_cell_k<float><<<D / 4, 256, 0, stream>>>(w_ih, w_hh, b_ih, b_hh,
                                                        embt + (size_t)3 * V * D, sel_func,
                                                        h_in, c_in, h_out, c_out, nullptr);
  swap_state();
  dec_sample_k<<<V / 4, 256, 0, stream>>>(dec_w + (size_t)4 * V * D,
                                          dec_b + (size_t)4 * V, c_in, logits,
                                          counters + step, step,
                                          out + step, out + 9 + step, out + 18 + step,
                                          sel_func);
}

// Round 3
// 345.677 us; speedup vs baseline: 2.8787x; 2.8787x over previous
//
#include <hip/hip_runtime.h>
#include <stdint.h>

#define D 2048
#define V 4096
#define TINYF 1.17549435e-38f
#define NINF (-__builtin_huge_valf())

// ---------------- threefry (JAX partitionable scheme, verified exact R1/R2) --------
__device__ __forceinline__ void tf_block(uint32_t k0, uint32_t k1, uint32_t x0, uint32_t x1,
                                         uint32_t& o0, uint32_t& o1) {
  uint32_t ks2 = k0 ^ k1 ^ 0x1BD11BDAu;
  uint32_t ks[3] = {k0, k1, ks2};
  x0 += k0; x1 += k1;
  const uint32_t rotA[4] = {13u, 15u, 26u, 6u};
  const uint32_t rotB[4] = {17u, 29u, 16u, 24u};
#pragma unroll
  for (int i = 0; i < 5; ++i) {
    const uint32_t* rot = (i & 1) ? rotB : rotA;
#pragma unroll
    for (int j = 0; j < 4; ++j) {
      uint32_t r = rot[j];
      x0 += x1;
      x1 = (x1 << r) | (x1 >> (32u - r));
      x1 ^= x0;
    }
    x0 += ks[(i + 1) % 3];
    x1 += ks[(i + 2) % 3] + (uint32_t)(i + 1);
  }
  o0 = x0; o1 = x1;
}

__device__ __forceinline__ float gumbel_at(uint32_t k1, uint32_t k2, int i) {
  uint32_t o0, o1;
  tf_block(k1, k2, 0u, (uint32_t)i, o0, o1);
  uint32_t bits = o0 ^ o1;
  float u = __uint_as_float((bits >> 9) | 0x3F800000u) - 1.0f;
  u = fmaxf(TINYF, u + TINYF);
  return -logf(-logf(u));
}

// ---------------- row-dot helpers --------------------------------------------------
__device__ __forceinline__ float row_dot(const float* __restrict__ row,
                                         const float* __restrict__ xs, int lane) {
  float a = 0.f;
#pragma unroll
  for (int k = lane * 4; k < D; k += 256) {
    float4 w = *(const float4*)(row + k);
    float4 x = *(const float4*)(xs + k);
    a += w.x * x.x + w.y * x.y + w.z * x.z + w.w * x.w;
  }
  return a;
}

__device__ __forceinline__ float row_dot(const uint16_t* __restrict__ row,
                                         const float* __restrict__ xs, int lane) {
  float a = 0.f;
#pragma unroll
  for (int k = lane * 8; k < D; k += 512) {
    uint4 u = *(const uint4*)(row + k);
    float4 x0 = *(const float4*)(xs + k);
    float4 x1 = *(const float4*)(xs + k + 4);
    a += __uint_as_float(u.x << 16) * x0.x + __uint_as_float(u.x & 0xFFFF0000u) * x0.y;
    a += __uint_as_float(u.y << 16) * x0.z + __uint_as_float(u.y & 0xFFFF0000u) * x0.w;
    a += __uint_as_float(u.z << 16) * x1.x + __uint_as_float(u.z & 0xFFFF0000u) * x1.y;
    a += __uint_as_float(u.w << 16) * x1.z + __uint_as_float(u.w & 0xFFFF0000u) * x1.w;
  }
  return a;
}

// ---------------- f32 -> bf16 (RNE) weight pack: w_ih, w_hh, lin1_w, lin2_w --------
__global__ void convert_k(const float* __restrict__ wih, const float* __restrict__ whh,
                          const float* __restrict__ l1, const float* __restrict__ l2,
                          uint16_t* __restrict__ dwih, uint16_t* __restrict__ dwhh,
                          uint16_t* __restrict__ dl1, uint16_t* __restrict__ dl2) {
  size_t gid = (size_t)blockIdx.x * 256 + threadIdx.x;  // 8-float chunk id
  const size_t C1 = (size_t)4 * D * D / 8;
  const size_t C2 = 2 * C1;
  const size_t C3 = C2 + (size_t)D * D / 8;
  const size_t C4 = C3 + (size_t)D * D / 8;
  const float* src; uint16_t* dst; size_t off;
  if (gid < C1)      { src = wih; dst = dwih; off = gid; }
  else if (gid < C2) { src = whh; dst = dwhh; off = gid - C1; }
  else if (gid < C3) { src = l1;  dst = dl1;  off = gid - C2; }
  else if (gid < C4) { src = l2;  dst = dl2;  off = gid - C3; }
  else return;
  const float4* s = (const float4*)(src + off * 8);
  float4 a = s[0], b = s[1];
  float v[8] = {a.x, a.y, a.z, a.w, b.x, b.y, b.z, b.w};
  uint32_t r[8];
#pragma unroll
  for (int t = 0; t < 8; ++t) {
    uint32_t x = __float_as_uint(v[t]);
    x = x + 0x7FFFu + ((x >> 16) & 1u);   // round-to-nearest-even
    r[t] = x >> 16;
  }
  uint4 o;
  o.x = r[0] | (r[1] << 16);
  o.y = r[2] | (r[3] << 16);
  o.z = r[4] | (r[5] << 16);
  o.w = r[6] | (r[7] << 16);
  *(uint4*)(dst + off * 8) = o;
}

// ---------------- LSTM cell: wave per output row, 4 rows/block ---------------------
template <typename WT>
__global__ void lstm_cell_k(const WT* __restrict__ w_ih, const WT* __restrict__ w_hh,
                            const float* __restrict__ b_ih, const float* __restrict__ b_hh,
                            const float* __restrict__ x_base, const int* __restrict__ x_idx,
                            const float* __restrict__ h_in, const float* __restrict__ c_in,
                            float* __restrict__ h_out, float* __restrict__ c_out,
                            float* __restrict__ c_copy) {
  __shared__ float xs[D];
  __shared__ float hs[D];
  int tid = threadIdx.x;
  const float* x = x_base;
  if (x_idx) x += (size_t)(*x_idx) * D;
  for (int i = tid; i < D; i += 256) { xs[i] = x[i]; hs[i] = h_in ? h_in[i] : 0.f; }
  __syncthreads();
  int wave = tid >> 6, lane = tid & 63;
  int j = blockIdx.x * 4 + wave;
  float gv[4];
#pragma unroll
  for (int m = 0; m < 4; ++m) {
    float a = row_dot(w_ih + (size_t)(m * D + j) * D, xs, lane)
            + row_dot(w_hh + (size_t)(m * D + j) * D, hs, lane);
#pragma unroll
    for (int off = 32; off > 0; off >>= 1) a += __shfl_down(a, off, 64);
    gv[m] = a + b_ih[m * D + j] + b_hh[m * D + j];
  }
  if (lane == 0) {
    float ig = 1.f / (1.f + expf(-gv[0]));
    float fg = 1.f / (1.f + expf(-gv[1]));
    float gg = tanhf(gv[2]);
    float og = 1.f / (1.f + expf(-gv[3]));
    float ci = c_in ? c_in[j] : 0.f;
    float cn = fg * ci + ig * gg;
    float hn = og * tanhf(cn);
    c_out[j] = cn;
    h_out[j] = hn;
    if (c_copy) c_copy[j] = cn;
  }
}

// ---------------- lin1 + lin2 GEMVs in one launch (no cross-block sync) ------------
template <typename WT>
__global__ void lin12_k(const WT* __restrict__ l1w, const float* __restrict__ l1b,
                        const WT* __restrict__ l2w, const float* __restrict__ l2b,
                        const float* __restrict__ c, float* __restrict__ cw_dst,
                        float* __restrict__ qb) {
  __shared__ float xs[D];
  int tid = threadIdx.x;
  for (int i = tid; i < D; i += 256) xs[i] = c[i];
  __syncthreads();
  int wave = tid >> 6, lane = tid & 63;
  int b = blockIdx.x;
  const WT* Wp; const float* bp; float* dst; int row;
  if (b < 512) { row = b * 4 + wave; Wp = l1w; bp = l1b; dst = cw_dst; }
  else         { row = (b - 512) * 4 + wave; Wp = l2w; bp = l2b; dst = qb; }
  float a = row_dot(Wp + (size_t)row * D, xs, lane);
#pragma unroll
  for (int off = 32; off > 0; off >>= 1) a += __shfl_down(a, off, 64);
  if (lane == 0) dst[row] = a + bp[row];
}

// ---------------- generic f32 GEMV (decoders): wave/row, 4 rows/block --------------
__global__ void gemv_k(const float* __restrict__ W, const float* __restrict__ bias,
                       const float* __restrict__ c, float* __restrict__ y) {
  __shared__ float xs[D];
  int tid = threadIdx.x;
  for (int i = tid; i < D; i += 256) xs[i] = c[i];
  __syncthreads();
  int wave = tid >> 6, lane = tid & 63;
  int row = blockIdx.x * 4 + wave;
  float a = row_dot(W + (size_t)row * D, xs, lane);
#pragma unroll
  for (int off = 32; off > 0; off >>= 1) a += __shfl_down(a, off, 64);
  if (lane == 0) y[row] = a + bias[row];
}

// ---------------- attention logits + small-N sample, one block ---------------------
__global__ void attn_sample_k(const float* __restrict__ qb, const float* __restrict__ all_cw,
                              const float* __restrict__ lin3_w, const float* __restrict__ lin3_b,
                              int N, int step,
                              float* __restrict__ out_arc, float* __restrict__ out_ent,
                              float* __restrict__ out_lp, int* __restrict__ sel_out) {
  __shared__ float red[256];
  __shared__ float sl[8];
  int tid = threadIdx.x;
  for (int t = 0; t < N; ++t) {
    float s = 0.f;
    for (int k = tid; k < D; k += 256) s += tanhf(qb[k] + all_cw[(size_t)t * D + k]) * lin3_w[k];
    red[tid] = s; __syncthreads();
    for (int st = 128; st > 0; st >>= 1) { if (tid < st) red[tid] += red[tid + st]; __syncthreads(); }
    if (tid == 0) sl[t] = red[0] + lin3_b[0];
    __syncthreads();
  }
  if (tid == 0) {
    uint32_t k1, k2; tf_block(0u, 42u, 0u, (uint32_t)step, k1, k2);
    float m = NINF;
    for (int i = 0; i < N; ++i) m = fmaxf(m, sl[i]);
    float S = 0.f, T = 0.f;
    for (int i = 0; i < N; ++i) { float e = expf(sl[i] - m); S += e; T += e * (sl[i] - m); }
    float L = logf(S);
    float bv = NINF; int bi = 0;
    for (int i = 0; i < N; ++i) {
      float sc = gumbel_at(k1, k2, i) + sl[i];
      if (sc > bv) { bv = sc; bi = i; }
    }
    *out_arc = (float)bi;
    *out_ent = L - T / S;
    *out_lp  = sl[bi] - m - L;
    *sel_out = bi;
  }
}

// ---------------- V=4096 sampler, one block of 1024 --------------------------------
__global__ void sample_k(const float* __restrict__ logits, int step,
                         float* __restrict__ out_arc, float* __restrict__ out_ent,
                         float* __restrict__ out_lp, int* __restrict__ sel_out) {
  __shared__ float red[1024];
  __shared__ int redi[1024];
  int tid = threadIdx.x;
  uint32_t k1, k2; tf_block(0u, 42u, 0u, (uint32_t)step, k1, k2);
  float xv[4];
  float m = NINF, bv = NINF; int bi = 1 << 30;
#pragma unroll
  for (int t = 0; t < 4; ++t) {
    int i = tid + t * 1024;
    float x = logits[i];
    xv[t] = x;
    m = fmaxf(m, x);
    float sc = gumbel_at(k1, k2, i) + x;
    if (sc > bv) { bv = sc; bi = i; }   // within-thread: increasing i -> first-index ties
  }
  red[tid] = m; __syncthreads();
  for (int st = 512; st > 0; st >>= 1) { if (tid < st) red[tid] = fmaxf(red[tid], red[tid + st]); __syncthreads(); }
  m = red[0]; __syncthreads();
  float S = 0.f, T = 0.f;
#pragma unroll
  for (int t = 0; t < 4; ++t) { float e = expf(xv[t] - m); S += e; T += e * (xv[t] - m); }
  red[tid] = S; __syncthreads();
  for (int st = 512; st > 0; st >>= 1) { if (tid < st) red[tid] += red[tid + st]; __syncthreads(); }
  S = red[0]; __syncthreads();
  red[tid] = T; __syncthreads();
  for (int st = 512; st > 0; st >>= 1) { if (tid < st) red[tid] += red[tid + st]; __syncthreads(); }
  T = red[0]; __syncthreads();
  red[tid] = bv; redi[tid] = bi; __syncthreads();
  for (int st = 512; st > 0; st >>= 1) {
    if (tid < st) {
      float ov = red[tid + st]; int oi = redi[tid + st];
      if (ov > red[tid] || (ov == red[tid] && oi < redi[tid])) { red[tid] = ov; redi[tid] = oi; }
    }
    __syncthreads();
  }
  if (tid == 0) {
    float L = logf(S);
    int idx = redi[0];
    *out_arc = (float)idx;
    *out_ent = L - T / S;
    *out_lp  = logits[idx] - m - L;
    *sel_out = idx;
  }
}

// ---------------- host-side orchestration ------------------------------------------
extern "C" void kernel_launch(void* const* d_in, const int* in_sizes, int n_in,
                              void* d_out, int out_size, void* d_ws, size_t ws_size,
                              hipStream_t stream) {
  const float* emb0   = (const float*)d_in[0];
  const float* w_ih   = (const float*)d_in[1];
  const float* w_hh   = (const float*)d_in[2];
  const float* b_ih   = (const float*)d_in[3];
  const float* b_hh   = (const float*)d_in[4];
  const float* lin1_w = (const float*)d_in[5];
  const float* lin1_b = (const float*)d_in[6];
  const float* lin2_w = (const float*)d_in[7];
  const float* lin2_b = (const float*)d_in[8];
  const float* lin3_w = (const float*)d_in[9];
  const float* lin3_b = (const float*)d_in[10];
  const float* dec_w  = (const float*)d_in[11];
  const float* dec_b  = (const float*)d_in[12];
  const float* embt   = (const float*)d_in[13];

  float* out = (float*)d_out;  // [0..8]=arc, [9..17]=entropy, [18..26]=log_probs
  float* ws = (float*)d_ws;

  float* hA     = ws;
  float* cA     = ws + D;
  float* hB     = ws + 2 * D;
  float* cB     = ws + 3 * D;
  float* all_c  = ws + 4 * D;      // 4*D
  float* all_cw = ws + 8 * D;      // 4*D
  float* qb     = ws + 12 * D;     // D
  float* logits = ws + 13 * D;     // V = 2*D
  int* sel_skip = (int*)(ws + 15 * D);
  int* sel_func = (int*)(ws + 15 * D + 1);
  uint16_t* wih_bf = (uint16_t*)(ws + 15 * D + 64);
  uint16_t* whh_bf = wih_bf + (size_t)4 * D * D;
  uint16_t* l1_bf  = whh_bf + (size_t)4 * D * D;
  uint16_t* l2_bf  = l1_bf + (size_t)D * D;

  // bf16 weight cache needs ~84 MB of ws; fall back to f32 path if ws is small
  bool bf = ws_size >= ((size_t)95 << 20);

  if (bf) {
    convert_k<<<20480, 256, 0, stream>>>(w_ih, w_hh, lin1_w, lin2_w,
                                         wih_bf, whh_bf, l1_bf, l2_bf);
  }

  float* h_in = nullptr; float* c_in = nullptr;
  float* h_out = hA;     float* c_out = cA;
  int step = 0;

  auto swap_state = [&]() {
    h_in = h_out; c_in = c_out;
    h_out = (h_in == hA) ? hB : hA;
    c_out = (c_in == cA) ? cB : cA;
  };

  for (int layer = 0; layer < 4; ++layer) {
    const float* xb; const int* xi;
    if (layer == 0) { xb = emb0; xi = nullptr; }
    else            { xb = embt + (size_t)(layer - 1) * V * D; xi = sel_func; }
    if (bf) lstm_cell_k<uint16_t><<<D / 4, 256, 0, stream>>>(wih_bf, whh_bf, b_ih, b_hh, xb, xi,
                                                             h_in, c_in, h_out, c_out,
                                                             all_c + (size_t)layer * D);
    else    lstm_cell_k<float><<<D / 4, 256, 0, stream>>>(w_ih, w_hh, b_ih, b_hh, xb, xi,
                                                          h_in, c_in, h_out, c_out,
                                                          all_c + (size_t)layer * D);
    swap_state();

    if (bf) lin12_k<uint16_t><<<1024, 256, 0, stream>>>(l1_bf, lin1_b, l2_bf, lin2_b, c_in,
                                                        all_cw + (size_t)layer * D, qb);
    else    lin12_k<float><<<1024, 256, 0, stream>>>(lin1_w, lin1_b, lin2_w, lin2_b, c_in,
                                                     all_cw + (size_t)layer * D, qb);

    attn_sample_k<<<1, 256, 0, stream>>>(qb, all_cw, lin3_w, lin3_b, layer + 1, step,
                                         out + step, out + 9 + step, out + 18 + step, sel_skip);
    step++;

    if (bf) lstm_cell_k<uint16_t><<<D / 4, 256, 0, stream>>>(wih_bf, whh_bf, b_ih, b_hh,
                                                             all_c, sel_skip,
                                                             h_in, c_in, h_out, c_out, nullptr);
    else    lstm_cell_k<float><<<D / 4, 256, 0, stream>>>(w_ih, w_hh, b_ih, b_hh,
                                                          all_c, sel_skip,
                                                          h_in, c_in, h_out, c_out, nullptr);
    swap_state();

    gemv_k<<<V / 4, 256, 0, stream>>>(dec_w + (size_t)layer * V * D,
                                      dec_b + (size_t)layer * V, c_in, logits);
    sample_k<<<1, 1024, 0, stream>>>(logits, step,
                                     out + step, out + 9 + step, out + 18 + step, sel_func);
    step++;
  }

  // final cell + decode
  if (bf) lstm_cell_k<uint16_t><<<D / 4, 256, 0, stream>>>(wih_bf, whh_bf, b_ih, b_hh,
                                                           embt + (size_t)3 * V * D, sel_func,
                                                           h_in, c_in, h_out, c_out, nullptr);
  else    lstm_cell_k<float><<<D / 4, 256, 0, stream>>>(w_ih, w_hh, b_ih, b_hh,
                                                        embt + (size_t)3 * V * D, sel_func,
                                                        h_in, c_in, h_out, c_out, nullptr);
  swap_state();
  gemv_k<<<V / 4, 256, 0, stream>>>(dec_w + (size_t)4 * V * D,
                                    dec_b + (size_t)4 * V, c_in, logits);
  sample_k<<<1, 1024, 0, stream>>>(logits, step,
                                   out + step, out + 9 + step, out + 18 + step, sel_func);
}